// Round 1
// baseline (281.847 us; speedup 1.0000x reference)
//
#include <hip/hip_runtime.h>
#include <cstdint>

typedef unsigned short u16;
typedef __attribute__((ext_vector_type(8))) short short8;
typedef __attribute__((ext_vector_type(4))) float f32x4;

#define NTOK 2048
#define CDIM 1024
#define C3   3072
#define NH   8
#define HD   128

__device__ __forceinline__ float bf2f(u16 u) {
    return __uint_as_float(((unsigned)u) << 16);
}
__device__ __forceinline__ u16 f2bf(float f) {
    unsigned u = __float_as_uint(f);
    u += 0x7fffu + ((u >> 16) & 1u);
    return (u16)(u >> 16);
}

// ---------------------------------------------------------------- K1: f32->bf16
__global__ __launch_bounds__(256) void k_cast(const float* __restrict__ x,
                                              const float* __restrict__ w,
                                              u16* __restrict__ xb,
                                              u16* __restrict__ wb) {
    int t = blockIdx.x * blockDim.x + threadIdx.x;
    int stride = gridDim.x * blockDim.x;
    for (int i = t; i < (NTOK * CDIM) / 4; i += stride) {
        float4 v = ((const float4*)x)[i];
        ushort4 o;
        o.x = f2bf(v.x); o.y = f2bf(v.y); o.z = f2bf(v.z); o.w = f2bf(v.w);
        ((ushort4*)xb)[i] = o;
    }
    for (int i = t; i < (C3 * CDIM) / 4; i += stride) {
        float4 v = ((const float4*)w)[i];
        ushort4 o;
        o.x = f2bf(v.x); o.y = f2bf(v.y); o.z = f2bf(v.z); o.w = f2bf(v.w);
        ((ushort4*)wb)[i] = o;
    }
}

// ---------------------------------------------------------------- K2: generic bf16 GEMM, C = A[M,K] @ B[N,K]^T
// EPI 0: write bf16. EPI 1: write u8 (acc*scale > 0.75). EPI 2: write f32 scaled by 1/rowScale[row].
template <int EPI>
__global__ __launch_bounds__(256) void k_gemm_bt(const u16* __restrict__ A,
                                                 const u16* __restrict__ B,
                                                 void* __restrict__ Cv, int K,
                                                 int lda, int ldb, int ldc,
                                                 long long aBatch, long long bBatch,
                                                 long long cBatch,
                                                 const float* __restrict__ rowScale,
                                                 float scale) {
    __shared__ u16 As[128][40];
    __shared__ u16 Bs[128][40];
    const int tid = threadIdx.x;
    const int lane = tid & 63;
    const int wid = tid >> 6;
    const int wm = wid >> 1, wn = wid & 1;
    const int q = lane >> 4, l16 = lane & 15;
    const int m0 = blockIdx.y * 128, n0 = blockIdx.x * 128;
    const int z = blockIdx.z;
    const u16* Ab = A + (long long)z * aBatch;
    const u16* Bb = B + (long long)z * bBatch;

    f32x4 zero4 = {0.f, 0.f, 0.f, 0.f};
    f32x4 acc[4][4];
#pragma unroll
    for (int i = 0; i < 4; i++)
#pragma unroll
        for (int j = 0; j < 4; j++) acc[i][j] = zero4;

    for (int k0 = 0; k0 < K; k0 += 32) {
        __syncthreads();
        {
            int v = tid;
            int row = v >> 2, kc = (v & 3) * 8;
            *(short8*)&As[row][kc] =
                *(const short8*)&Ab[(long long)(m0 + row) * lda + k0 + kc];
            *(short8*)&Bs[row][kc] =
                *(const short8*)&Bb[(long long)(n0 + row) * ldb + k0 + kc];
            v = tid + 256;
            row = v >> 2; kc = (v & 3) * 8;
            *(short8*)&As[row][kc] =
                *(const short8*)&Ab[(long long)(m0 + row) * lda + k0 + kc];
            *(short8*)&Bs[row][kc] =
                *(const short8*)&Bb[(long long)(n0 + row) * ldb + k0 + kc];
        }
        __syncthreads();
        short8 af[4], bfr[4];
#pragma unroll
        for (int tm = 0; tm < 4; tm++)
            af[tm] = *(const short8*)&As[wm * 64 + tm * 16 + l16][q * 8];
#pragma unroll
        for (int tn = 0; tn < 4; tn++)
            bfr[tn] = *(const short8*)&Bs[wn * 64 + tn * 16 + l16][q * 8];
#pragma unroll
        for (int tm = 0; tm < 4; tm++)
#pragma unroll
            for (int tn = 0; tn < 4; tn++)
                acc[tm][tn] = __builtin_amdgcn_mfma_f32_16x16x32_bf16(
                    af[tm], bfr[tn], acc[tm][tn], 0, 0, 0);
    }

#pragma unroll
    for (int tm = 0; tm < 4; tm++) {
#pragma unroll
        for (int tn = 0; tn < 4; tn++) {
#pragma unroll
            for (int r = 0; r < 4; r++) {
                int row = m0 + wm * 64 + tm * 16 + q * 4 + r;
                int col = n0 + wn * 64 + tn * 16 + l16;
                float v = acc[tm][tn][r];
                long long off = (long long)z * cBatch + (long long)row * ldc + col;
                if (EPI == 0) {
                    ((u16*)Cv)[off] = f2bf(v);
                } else if (EPI == 1) {
                    ((unsigned char*)Cv)[off] = (v * scale > 0.75f) ? 1 : 0;
                } else {
                    float s = rowScale[(long long)z * NTOK + row];
                    ((float*)Cv)[off] = v / s;
                }
            }
        }
    }
}

// ---------------------------------------------------------------- K3 norm: per-row L2 normalize q/k/v heads
__global__ __launch_bounds__(256) void k_norm(const u16* __restrict__ qkv,
                                              u16* __restrict__ Qn,
                                              u16* __restrict__ Kn,
                                              u16* __restrict__ Vn,
                                              u16* __restrict__ Vt,
                                              float* __restrict__ out) {
    int n = blockIdx.x;
    int lane = threadIdx.x & 63;
    int w = threadIdx.x >> 6;
    for (int s = w; s < 24; s += 4) {
        int which = s >> 3;  // 0=q 1=k 2=v
        int h = s & 7;
        int d0 = lane * 2;
        const u16* src = qkv + (long long)n * C3 + which * CDIM + h * HD + d0;
        u16 u0 = src[0], u1 = src[1];
        float f0 = bf2f(u0), f1 = bf2f(u1);
        float ss = f0 * f0 + f1 * f1;
#pragma unroll
        for (int off = 1; off < 64; off <<= 1) ss += __shfl_xor(ss, off);
        float rn = rsqrtf(ss);
        u16* dst = (which == 0 ? Qn : which == 1 ? Kn : Vn) +
                   (long long)n * CDIM + h * HD + d0;
        ushort2 nv;
        nv.x = f2bf(f0 * rn);
        nv.y = f2bf(f1 * rn);
        *(ushort2*)dst = nv;
        if (which == 2) {
            float2 fo;
            fo.x = f0; fo.y = f1;
            *(float2*)&out[(long long)n * 2048 + 1024 + h * HD + d0] = fo;
            Vt[((long long)h * HD + d0) * NTOK + n] = u0;
            Vt[((long long)h * HD + d0 + 1) * NTOK + n] = u1;
        }
    }
}

// ---------------------------------------------------------------- K4: fused logits + exp (unnormalized), row sums
__global__ __launch_bounds__(256) void k_attn(const u16* __restrict__ Qn,
                                              const u16* __restrict__ Kn,
                                              const float* __restrict__ cls,
                                              u16* __restrict__ P,
                                              float* __restrict__ Srow) {
    __shared__ float rowS[16];
    const int h = blockIdx.y;
    const int i0 = blockIdx.x * 16;
    const int tid = threadIdx.x;
    const int lane = tid & 63, w = tid >> 6, q = lane >> 4, l16 = lane & 15;
    if (tid < 16) rowS[tid] = 0.f;
    __syncthreads();

    short8 af[4];
#pragma unroll
    for (int kt = 0; kt < 4; kt++)
        af[kt] = *(const short8*)&Qn[(long long)(i0 + l16) * CDIM + h * HD +
                                     kt * 32 + q * 8];
    float cls_i[4];
#pragma unroll
    for (int r = 0; r < 4; r++) cls_i[r] = cls[i0 + q * 4 + r] - 0.1f;

    float sum_r[4] = {0.f, 0.f, 0.f, 0.f};
    f32x4 zero4 = {0.f, 0.f, 0.f, 0.f};
    for (int jt = w * 32; jt < (w + 1) * 32; ++jt) {
        short8 bfr[4];
#pragma unroll
        for (int kt = 0; kt < 4; kt++)
            bfr[kt] = *(const short8*)&Kn[(long long)(jt * 16 + l16) * CDIM +
                                          h * HD + kt * 32 + q * 8];
        f32x4 acc = zero4;
#pragma unroll
        for (int kt = 0; kt < 4; kt++)
            acc = __builtin_amdgcn_mfma_f32_16x16x32_bf16(af[kt], bfr[kt], acc,
                                                          0, 0, 0);
        int j = jt * 16 + l16;
        float cj = cls[j];
        float sc = 25.f * cj;
        u16* pdst = P + ((long long)(h * NTOK + i0 + q * 4)) * NTOK + j;
#pragma unroll
        for (int r = 0; r < 4; r++) {
            float m = (cj > cls_i[r]) ? 1.f : 0.f;
            float l = acc[r] * sc * m;
            float e = __expf(l);
            sum_r[r] += e;
            pdst[(long long)r * NTOK] = f2bf(e);
        }
    }
#pragma unroll
    for (int r = 0; r < 4; r++) {
        float s = sum_r[r];
        s += __shfl_xor(s, 1);
        s += __shfl_xor(s, 2);
        s += __shfl_xor(s, 4);
        s += __shfl_xor(s, 8);
        if (l16 == 0) atomicAdd(&rowS[q * 4 + r], s);
    }
    __syncthreads();
    if (tid < 16) Srow[h * NTOK + i0 + tid] = rowS[tid];
}

// ---------------------------------------------------------------- K5: output2 = renormed masked softmax of head-mean attn
__global__ __launch_bounds__(256) void k_out2(const u16* __restrict__ P,
                                              const float* __restrict__ Srow,
                                              const unsigned char* __restrict__ mask,
                                              float* __restrict__ out2) {
    __shared__ float red[256];
    const int i = blockIdx.x;
    const int t = threadIdx.x;
    float invS[NH];
#pragma unroll
    for (int h = 0; h < NH; h++) invS[h] = 1.f / (8.f * Srow[h * NTOK + i]);
    const int c0 = t * 8;
    float a[8] = {0.f, 0.f, 0.f, 0.f, 0.f, 0.f, 0.f, 0.f};
#pragma unroll
    for (int h = 0; h < NH; h++) {
        short8 p = *(const short8*)&P[((long long)h * NTOK + i) * NTOK + c0];
#pragma unroll
        for (int k = 0; k < 8; k++) a[k] += bf2f((u16)p[k]) * invS[h];
    }
    const unsigned char* mrow = mask + (long long)i * NTOK + c0;
    float e[8];
    unsigned char mk[8];
    float part = 0.f;
#pragma unroll
    for (int k = 0; k < 8; k++) {
        e[k] = __expf(a[k]);
        mk[k] = mrow[k];
        if (mk[k]) part += e[k];
    }
    red[t] = part;
    __syncthreads();
    for (int s = 128; s > 0; s >>= 1) {
        if (t < s) red[t] += red[t + s];
        __syncthreads();
    }
    float invT = 1.f / red[0];
    float o[8];
#pragma unroll
    for (int k = 0; k < 8; k++) o[k] = mk[k] ? e[k] * invT : 0.f;
    float4 o0, o1;
    o0.x = o[0]; o0.y = o[1]; o0.z = o[2]; o0.w = o[3];
    o1.x = o[4]; o1.y = o[5]; o1.z = o[6]; o1.w = o[7];
    float* dst = out2 + (long long)i * NTOK + c0;
    *(float4*)dst = o0;
    *(float4*)(dst + 4) = o1;
}

// ---------------------------------------------------------------- launcher
extern "C" void kernel_launch(void* const* d_in, const int* in_sizes, int n_in,
                              void* d_out, int out_size, void* d_ws,
                              size_t ws_size, hipStream_t stream) {
    (void)in_sizes; (void)n_in; (void)out_size; (void)ws_size;
    const float* x = (const float*)d_in[0];
    const float* cls = (const float*)d_in[1];
    // d_in[2] = fg_score: unused by the reference
    const float* Wq = (const float*)d_in[3];
    float* out = (float*)d_out;
    char* ws = (char*)d_ws;

    u16* Xb = (u16*)(ws + 0);                      //  4 MB  [2048,1024]
    u16* Wb = (u16*)(ws + 4194304);                //  6 MB  [3072,1024]
    u16* QKVb = (u16*)(ws + 10485760);             // 12.6MB [2048,3072]
    u16* Qn = (u16*)(ws + 23068672);               //  4 MB
    u16* Kn = (u16*)(ws + 27262976);               //  4 MB
    u16* Vn = (u16*)(ws + 31457280);               //  4 MB
    u16* Vt = (u16*)(ws + 35651584);               //  4 MB  [8,128,2048]
    unsigned char* mask = (unsigned char*)(ws + 39845888);  // 4 MB [2048,2048]
    u16* P = (u16*)(ws + 44040192);                // 67 MB [8,2048,2048]
    float* Srow = (float*)(ws + 111149056);        // 64 KB [8,2048]

    // 1. cast x and W to bf16
    k_cast<<<1024, 256, 0, stream>>>(x, Wq, Xb, Wb);

    // 2. QKV = Xb @ Wb^T  -> bf16 [2048,3072]
    k_gemm_bt<0><<<dim3(C3 / 128, NTOK / 128, 1), 256, 0, stream>>>(
        Xb, Wb, QKVb, CDIM, CDIM, CDIM, C3, 0, 0, 0, nullptr, 1.f);

    // 3. normalize q/k/v, write x_ori, transposed Vt
    k_norm<<<NTOK, 256, 0, stream>>>(QKVb, Qn, Kn, Vn, Vt, out);

    // 4. sim mask = (Vn @ Vn^T / 8 > 0.75) -> u8
    k_gemm_bt<1><<<dim3(16, 16, 1), 256, 0, stream>>>(
        Vn, Vn, mask, CDIM, CDIM, CDIM, NTOK, 0, 0, 0, nullptr, 0.125f);

    // 5. fused logits + exp -> P (unnormalized, bf16), Srow
    k_attn<<<dim3(128, NH), 256, 0, stream>>>(Qn, Kn, cls, P, Srow);

    // 6. x = (P @ V) / S  -> d_out cols [h*128, h*128+128)
    k_gemm_bt<2><<<dim3(1, 16, NH), 256, 0, stream>>>(
        P, Vt, out, NTOK, NTOK, NTOK, 2048, (long long)NTOK * NTOK,
        (long long)HD * NTOK, HD, Srow, 1.f);

    // 7. output2
    k_out2<<<NTOK, 256, 0, stream>>>(P, Srow, mask, out + (long long)NTOK * 2048);
}

// Round 2
// 250.016 us; speedup vs baseline: 1.1273x; 1.1273x over previous
//
#include <hip/hip_runtime.h>
#include <cstdint>

typedef unsigned short u16;
typedef __attribute__((ext_vector_type(8))) short short8;
typedef __attribute__((ext_vector_type(4))) float f32x4;

#define NTOK 2048
#define CDIM 1024
#define C3   3072
#define NH   8
#define HD   128

__device__ __forceinline__ float bf2f(u16 u) {
    return __uint_as_float(((unsigned)u) << 16);
}
__device__ __forceinline__ u16 f2bf(float f) {
    unsigned u = __float_as_uint(f);
    u += 0x7fffu + ((u >> 16) & 1u);
    return (u16)(u >> 16);
}

// ---------------------------------------------------------------- K1: f32->bf16
__global__ __launch_bounds__(256) void k_cast(const float* __restrict__ x,
                                              const float* __restrict__ w,
                                              u16* __restrict__ xb,
                                              u16* __restrict__ wb) {
    int t = blockIdx.x * blockDim.x + threadIdx.x;
    int stride = gridDim.x * blockDim.x;
    for (int i = t; i < (NTOK * CDIM) / 4; i += stride) {
        float4 v = ((const float4*)x)[i];
        ushort4 o;
        o.x = f2bf(v.x); o.y = f2bf(v.y); o.z = f2bf(v.z); o.w = f2bf(v.w);
        ((ushort4*)xb)[i] = o;
    }
    for (int i = t; i < (C3 * CDIM) / 4; i += stride) {
        float4 v = ((const float4*)w)[i];
        ushort4 o;
        o.x = f2bf(v.x); o.y = f2bf(v.y); o.z = f2bf(v.z); o.w = f2bf(v.w);
        ((ushort4*)wb)[i] = o;
    }
}

// ---------------------------------------------------------------- K2: generic bf16 GEMM, C = A[M,K] @ B[N,K]^T
// EPI 0: write bf16. EPI 1: write u8 (acc*scale > 0.75).
template <int EPI>
__global__ __launch_bounds__(256) void k_gemm_bt(const u16* __restrict__ A,
                                                 const u16* __restrict__ B,
                                                 void* __restrict__ Cv, int K,
                                                 int lda, int ldb, int ldc,
                                                 float scale) {
    __shared__ u16 As[128][40];
    __shared__ u16 Bs[128][40];
    const int tid = threadIdx.x;
    const int lane = tid & 63;
    const int wid = tid >> 6;
    const int wm = wid >> 1, wn = wid & 1;
    const int q = lane >> 4, l16 = lane & 15;
    const int m0 = blockIdx.y * 128, n0 = blockIdx.x * 128;

    f32x4 zero4 = {0.f, 0.f, 0.f, 0.f};
    f32x4 acc[4][4];
#pragma unroll
    for (int i = 0; i < 4; i++)
#pragma unroll
        for (int j = 0; j < 4; j++) acc[i][j] = zero4;

    for (int k0 = 0; k0 < K; k0 += 32) {
        __syncthreads();
        {
            int v = tid;
            int row = v >> 2, kc = (v & 3) * 8;
            *(short8*)&As[row][kc] =
                *(const short8*)&A[(long long)(m0 + row) * lda + k0 + kc];
            *(short8*)&Bs[row][kc] =
                *(const short8*)&B[(long long)(n0 + row) * ldb + k0 + kc];
            v = tid + 256;
            row = v >> 2; kc = (v & 3) * 8;
            *(short8*)&As[row][kc] =
                *(const short8*)&A[(long long)(m0 + row) * lda + k0 + kc];
            *(short8*)&Bs[row][kc] =
                *(const short8*)&B[(long long)(n0 + row) * ldb + k0 + kc];
        }
        __syncthreads();
        short8 af[4], bfr[4];
#pragma unroll
        for (int tm = 0; tm < 4; tm++)
            af[tm] = *(const short8*)&As[wm * 64 + tm * 16 + l16][q * 8];
#pragma unroll
        for (int tn = 0; tn < 4; tn++)
            bfr[tn] = *(const short8*)&Bs[wn * 64 + tn * 16 + l16][q * 8];
#pragma unroll
        for (int tm = 0; tm < 4; tm++)
#pragma unroll
            for (int tn = 0; tn < 4; tn++)
                acc[tm][tn] = __builtin_amdgcn_mfma_f32_16x16x32_bf16(
                    af[tm], bfr[tn], acc[tm][tn], 0, 0, 0);
    }

#pragma unroll
    for (int tm = 0; tm < 4; tm++) {
#pragma unroll
        for (int tn = 0; tn < 4; tn++) {
#pragma unroll
            for (int r = 0; r < 4; r++) {
                int row = m0 + wm * 64 + tm * 16 + q * 4 + r;
                int col = n0 + wn * 64 + tn * 16 + l16;
                float v = acc[tm][tn][r];
                long long off = (long long)row * ldc + col;
                if (EPI == 0) {
                    ((u16*)Cv)[off] = f2bf(v);
                } else {
                    ((unsigned char*)Cv)[off] = (v * scale > 0.75f) ? 1 : 0;
                }
            }
        }
    }
}

// ---------------------------------------------------------------- K3: per-row L2 normalize q/k/v heads + x_ori
__global__ __launch_bounds__(256) void k_norm(const u16* __restrict__ qkv,
                                              u16* __restrict__ Qn,
                                              u16* __restrict__ Kn,
                                              u16* __restrict__ Vn,
                                              float* __restrict__ out) {
    int n = blockIdx.x;
    int lane = threadIdx.x & 63;
    int w = threadIdx.x >> 6;
    for (int s = w; s < 24; s += 4) {
        int which = s >> 3;  // 0=q 1=k 2=v
        int h = s & 7;
        int d0 = lane * 2;
        const u16* src = qkv + (long long)n * C3 + which * CDIM + h * HD + d0;
        u16 u0 = src[0], u1 = src[1];
        float f0 = bf2f(u0), f1 = bf2f(u1);
        float ss = f0 * f0 + f1 * f1;
#pragma unroll
        for (int off = 1; off < 64; off <<= 1) ss += __shfl_xor(ss, off);
        float rn = rsqrtf(ss);
        u16* dst = (which == 0 ? Qn : which == 1 ? Kn : Vn) +
                   (long long)n * CDIM + h * HD + d0;
        ushort2 nv;
        nv.x = f2bf(f0 * rn);
        nv.y = f2bf(f1 * rn);
        *(ushort2*)dst = nv;
        if (which == 2) {
            float2 fo;
            fo.x = f0; fo.y = f1;
            *(float2*)&out[(long long)n * 2048 + 1024 + h * HD + d0] = fo;
        }
    }
}

// ---------------------------------------------------------------- K3b: tiled transpose Vt[c][n] = v[n][c] (raw v)
__global__ __launch_bounds__(256) void k_vt(const u16* __restrict__ qkv,
                                            u16* __restrict__ Vt) {
    __shared__ u16 T[64][72];
    const int n0 = blockIdx.x * 64;
    const int c0 = blockIdx.y * 64;
    const int tid = threadIdx.x;
    {
        int nl = tid >> 2, cc = (tid & 3) * 16;
        const u16* src = &qkv[(long long)(n0 + nl) * C3 + 2 * CDIM + c0 + cc];
        *(short8*)&T[nl][cc] = *(const short8*)&src[0];
        *(short8*)&T[nl][cc + 8] = *(const short8*)&src[8];
    }
    __syncthreads();
    {
        int cl = tid >> 2, nc = (tid & 3) * 16;
        ushort va[16];
#pragma unroll
        for (int i = 0; i < 16; i++) va[i] = T[nc + i][cl];
        u16* dst = &Vt[(long long)(c0 + cl) * NTOK + n0 + nc];
        *(short8*)&dst[0] = *(short8*)&va[0];
        *(short8*)&dst[8] = *(short8*)&va[8];
    }
}

// ---------------------------------------------------------------- K4: fused logits+exp (unnormalized) -> P, row sums
__global__ __launch_bounds__(256) void k_attn2(const u16* __restrict__ Qn,
                                               const u16* __restrict__ Kn,
                                               const float* __restrict__ cls,
                                               u16* __restrict__ P,
                                               float* __restrict__ Srow) {
    __shared__ u16 Qs[64][128];
    __shared__ u16 Kf[8192];  // fragment-ready: slot ((tn*4+kt)*64+lane), 8 u16 each
    __shared__ float rowS[64];
    const int h = blockIdx.y;
    const int i0 = blockIdx.x * 64;
    const int tid = threadIdx.x, lane = tid & 63, wid = tid >> 6;
    const int q = lane >> 4, l16 = lane & 15;
    const int wm = wid >> 1, wn = wid & 1;  // wave grid: 2 (rows) x 2 (cols)

    if (tid < 64) rowS[tid] = 0.f;
    {
        int r = tid >> 2, c = (tid & 3) * 32;
        const u16* src = &Qn[(long long)(i0 + r) * CDIM + h * HD + c];
        *(short8*)&Qs[r][c]      = *(const short8*)&src[0];
        *(short8*)&Qs[r][c + 8]  = *(const short8*)&src[8];
        *(short8*)&Qs[r][c + 16] = *(const short8*)&src[16];
        *(short8*)&Qs[r][c + 24] = *(const short8*)&src[24];
    }
    __syncthreads();

    short8 af[2][4];
#pragma unroll
    for (int m = 0; m < 2; m++)
#pragma unroll
        for (int kt = 0; kt < 4; kt++)
            af[m][kt] = *(const short8*)&Qs[wm * 32 + m * 16 + l16][kt * 32 + q * 8];

    float cls_i[2][4];
#pragma unroll
    for (int m = 0; m < 2; m++)
#pragma unroll
        for (int r = 0; r < 4; r++)
            cls_i[m][r] = cls[i0 + wm * 32 + m * 16 + q * 4 + r] - 0.1f;

    float sums[2][4] = {{0.f, 0.f, 0.f, 0.f}, {0.f, 0.f, 0.f, 0.f}};

    for (int j0 = 0; j0 < NTOK; j0 += 64) {
        __syncthreads();
        {
            int r = tid >> 2;
            int tn = r >> 4, s16 = r & 15;
            const u16* src = &Kn[(long long)(j0 + r) * CDIM + h * HD + (tid & 3) * 32];
#pragma unroll
            for (int i = 0; i < 4; i++) {
                int chunk = (tid & 3) * 4 + i;
                int kt = chunk >> 2, qq = chunk & 3;
                int slot = (tn * 4 + kt) * 64 + qq * 16 + s16;
                *(short8*)&Kf[slot * 8] = *(const short8*)&src[i * 8];
            }
        }
        __syncthreads();
#pragma unroll
        for (int tn = 0; tn < 2; tn++) {
            int tng = wn * 2 + tn;
            short8 bfr[4];
#pragma unroll
            for (int kt = 0; kt < 4; kt++)
                bfr[kt] = *(const short8*)&Kf[((tng * 4 + kt) * 64 + lane) * 8];
            int j = j0 + tng * 16 + l16;
            float cj = cls[j];
            float sc = 25.f * cj;
#pragma unroll
            for (int m = 0; m < 2; m++) {
                f32x4 acc = {0.f, 0.f, 0.f, 0.f};
#pragma unroll
                for (int kt = 0; kt < 4; kt++)
                    acc = __builtin_amdgcn_mfma_f32_16x16x32_bf16(af[m][kt], bfr[kt],
                                                                  acc, 0, 0, 0);
                u16* pdst = &P[((long long)(h * NTOK + i0 + wm * 32 + m * 16 + q * 4)) * NTOK + j];
#pragma unroll
                for (int r = 0; r < 4; r++) {
                    float mk = (cj > cls_i[m][r]) ? 1.f : 0.f;
                    float e = __expf(acc[r] * sc * mk);
                    sums[m][r] += e;
                    pdst[(long long)r * NTOK] = f2bf(e);
                }
            }
        }
    }
#pragma unroll
    for (int m = 0; m < 2; m++)
#pragma unroll
        for (int r = 0; r < 4; r++) {
            float s = sums[m][r];
            s += __shfl_xor(s, 1);
            s += __shfl_xor(s, 2);
            s += __shfl_xor(s, 4);
            s += __shfl_xor(s, 8);
            if (l16 == 0) atomicAdd(&rowS[wm * 32 + m * 16 + q * 4 + r], s);
        }
    __syncthreads();
    if (tid < 64) Srow[h * NTOK + i0 + tid] = rowS[tid];
}

// ---------------------------------------------------------------- K5: x = (P @ V^T') / S, 64x128 tiles
__global__ __launch_bounds__(256) void k_pv(const u16* __restrict__ P,
                                            const u16* __restrict__ Vt,
                                            const float* __restrict__ Srow,
                                            float* __restrict__ out) {
    __shared__ u16 As[64][32];
    __shared__ u16 Bs[128][32];
    const int h = blockIdx.z;
    const int i0 = blockIdx.y * 64;
    const int tid = threadIdx.x, lane = tid & 63, wid = tid >> 6;
    const int q = lane >> 4, l16 = lane & 15;
    const int wm = wid >> 1, wn = wid & 1;
    const u16* Pb = P + (long long)h * NTOK * NTOK;
    const u16* Vb = Vt + (long long)h * HD * NTOK;

    f32x4 zero4 = {0.f, 0.f, 0.f, 0.f};
    f32x4 acc[2][4];
#pragma unroll
    for (int m = 0; m < 2; m++)
#pragma unroll
        for (int n = 0; n < 4; n++) acc[m][n] = zero4;

    for (int k0 = 0; k0 < NTOK; k0 += 32) {
        __syncthreads();
        *(short8*)&As[tid >> 2][(tid & 3) * 8] =
            *(const short8*)&Pb[(long long)(i0 + (tid >> 2)) * NTOK + k0 + (tid & 3) * 8];
        {
            int r = tid >> 1, c = (tid & 1) * 16;
            const u16* s = &Vb[(long long)r * NTOK + k0 + c];
            *(short8*)&Bs[r][c] = *(const short8*)&s[0];
            *(short8*)&Bs[r][c + 8] = *(const short8*)&s[8];
        }
        __syncthreads();
        short8 af[2], bfr[4];
#pragma unroll
        for (int m = 0; m < 2; m++)
            af[m] = *(const short8*)&As[wm * 32 + m * 16 + l16][q * 8];
#pragma unroll
        for (int n = 0; n < 4; n++)
            bfr[n] = *(const short8*)&Bs[wn * 64 + n * 16 + l16][q * 8];
#pragma unroll
        for (int m = 0; m < 2; m++)
#pragma unroll
            for (int n = 0; n < 4; n++)
                acc[m][n] = __builtin_amdgcn_mfma_f32_16x16x32_bf16(af[m], bfr[n],
                                                                    acc[m][n], 0, 0, 0);
    }

#pragma unroll
    for (int m = 0; m < 2; m++) {
#pragma unroll
        for (int n = 0; n < 4; n++) {
#pragma unroll
            for (int r = 0; r < 4; r++) {
                int row = i0 + wm * 32 + m * 16 + q * 4 + r;
                int col = wn * 64 + n * 16 + l16;
                float s = Srow[h * NTOK + row];
                out[(long long)row * 2048 + h * HD + col] = acc[m][n][r] / s;
            }
        }
    }
}

// ---------------------------------------------------------------- K6: output2 = renormed masked softmax of head-mean attn
__global__ __launch_bounds__(256) void k_out2(const u16* __restrict__ P,
                                              const float* __restrict__ Srow,
                                              const unsigned char* __restrict__ mask,
                                              float* __restrict__ out2) {
    __shared__ float red[256];
    const int i = blockIdx.x;
    const int t = threadIdx.x;
    float invS[NH];
#pragma unroll
    for (int h = 0; h < NH; h++) invS[h] = 1.f / (8.f * Srow[h * NTOK + i]);
    const int c0 = t * 8;
    float a[8] = {0.f, 0.f, 0.f, 0.f, 0.f, 0.f, 0.f, 0.f};
#pragma unroll
    for (int h = 0; h < NH; h++) {
        short8 p = *(const short8*)&P[((long long)h * NTOK + i) * NTOK + c0];
#pragma unroll
        for (int k = 0; k < 8; k++) a[k] += bf2f((u16)p[k]) * invS[h];
    }
    const unsigned char* mrow = mask + (long long)i * NTOK + c0;
    float e[8];
    unsigned char mk[8];
    float part = 0.f;
#pragma unroll
    for (int k = 0; k < 8; k++) {
        e[k] = __expf(a[k]);
        mk[k] = mrow[k];
        if (mk[k]) part += e[k];
    }
    red[t] = part;
    __syncthreads();
    for (int s = 128; s > 0; s >>= 1) {
        if (t < s) red[t] += red[t + s];
        __syncthreads();
    }
    float invT = 1.f / red[0];
    float o[8];
#pragma unroll
    for (int k = 0; k < 8; k++) o[k] = mk[k] ? e[k] * invT : 0.f;
    float4 o0, o1;
    o0.x = o[0]; o0.y = o[1]; o0.z = o[2]; o0.w = o[3];
    o1.x = o[4]; o1.y = o[5]; o1.z = o[6]; o1.w = o[7];
    float* dst = out2 + (long long)i * NTOK + c0;
    *(float4*)dst = o0;
    *(float4*)(dst + 4) = o1;
}

// ---------------------------------------------------------------- launcher
extern "C" void kernel_launch(void* const* d_in, const int* in_sizes, int n_in,
                              void* d_out, int out_size, void* d_ws,
                              size_t ws_size, hipStream_t stream) {
    (void)in_sizes; (void)n_in; (void)out_size; (void)ws_size;
    const float* x = (const float*)d_in[0];
    const float* cls = (const float*)d_in[1];
    // d_in[2] = fg_score: unused by the reference
    const float* Wq = (const float*)d_in[3];
    float* out = (float*)d_out;
    char* ws = (char*)d_ws;

    u16* Xb = (u16*)(ws + 0);                      //  4 MB  [2048,1024]
    u16* Wb = (u16*)(ws + 4194304);                //  6 MB  [3072,1024]
    u16* QKVb = (u16*)(ws + 10485760);             // 12.6MB [2048,3072]
    u16* Qn = (u16*)(ws + 23068672);               //  4 MB
    u16* Kn = (u16*)(ws + 27262976);               //  4 MB
    u16* Vn = (u16*)(ws + 31457280);               //  4 MB
    u16* Vt = (u16*)(ws + 35651584);               //  4 MB  [1024,2048]
    unsigned char* mask = (unsigned char*)(ws + 39845888);  // 4 MB [2048,2048]
    u16* P = (u16*)(ws + 44040192);                // 67 MB [8,2048,2048]
    float* Srow = (float*)(ws + 111149056);        // 64 KB [8,2048]

    // 1. cast x and W to bf16
    k_cast<<<1024, 256, 0, stream>>>(x, Wq, Xb, Wb);

    // 2. QKV = Xb @ Wb^T  -> bf16 [2048,3072]
    k_gemm_bt<0><<<dim3(C3 / 128, NTOK / 128), 256, 0, stream>>>(
        Xb, Wb, QKVb, CDIM, CDIM, CDIM, C3, 1.f);

    // 3. normalize q/k/v, write x_ori
    k_norm<<<NTOK, 256, 0, stream>>>(QKVb, Qn, Kn, Vn, out);

    // 3b. Vt = v^T (raw v), tiled transpose
    k_vt<<<dim3(NTOK / 64, CDIM / 64), 256, 0, stream>>>(QKVb, Vt);

    // 4. sim mask = (Vn @ Vn^T / 8 > 0.75) -> u8
    k_gemm_bt<1><<<dim3(16, 16), 256, 0, stream>>>(
        Vn, Vn, mask, CDIM, CDIM, CDIM, NTOK, 0.125f);

    // 5. fused logits + exp -> P (unnormalized bf16), Srow
    k_attn2<<<dim3(NTOK / 64, NH), 256, 0, stream>>>(Qn, Kn, cls, P, Srow);

    // 6. x = (P @ V) / S  -> d_out cols [h*128, h*128+128)
    k_pv<<<dim3(1, NTOK / 64, NH), 256, 0, stream>>>(P, Vt, Srow, out);

    // 7. output2
    k_out2<<<NTOK, 256, 0, stream>>>(P, Srow, mask, out + (long long)NTOK * 2048);
}